// Round 4
// baseline (90.480 us; speedup 1.0000x reference)
//
#include <hip/hip_runtime.h>
#include <hip/hip_bf16.h>

// Resonance synth: out(b,e,n) = sum_f env_f(n) * sin(2*pi*freq_f*(n+1))
//   freq_f = (MIN + SCALE*f0_be)*(f+1), aliased (>=1.0) harmonics contribute 0
//   env_f(n) = linear frame->sample interp of res^(t+1), 256 samples/frame.
//
// Round 4 (stall attack):
//  - R[] uniform per block -> SGPRs via readfirstlane (state = E[32] only)
//  - 4 independent accumulators (break the 32-deep fma chain)
//  - per-block trans (exp2/log2) computed once by 32 lanes, LDS broadcast;
//    within a block frame-index+1 is {4y, 4y+1} -> env init is one select-mul
//  - k-loops NOT unrolled (code ~6 KB, i-cache safe); f-loop unrolled
//  - __launch_bounds__(256,7): 73-VGPR cap, 7 waves/SIMD resident

#define NSAMP 32768
#define NFRM  128
#define NF    32
#define NPAIR 64
#define CHUNKS 32
#define CHUNK (NSAMP / CHUNKS)   // 1024 samples per block
#define KIT   (CHUNK / 256)      // 4 samples per thread

__device__ __forceinline__ float ldin(const void* p, int i, bool isbf) {
    if (isbf) {
        unsigned int w = ((unsigned int)((const unsigned short*)p)[i]) << 16;
        float f; __builtin_memcpy(&f, &w, 4); return f;
    }
    return ((const float*)p)[i];
}

// force a block-uniform float into an SGPR
__device__ __forceinline__ float rfl(float x) {
    int i; __builtin_memcpy(&i, &x, 4);
    i = __builtin_amdgcn_readfirstlane(i);
    float f; __builtin_memcpy(&f, &i, 4); return f;
}

extern "C" __global__ __launch_bounds__(256, 7)
void reson_kernel(const void* __restrict__ f0p,
                  const void* __restrict__ resp,
                  const void* __restrict__ facp,
                  void* __restrict__ outp)
{
    // dtype sniff: factors[0]==1.0f -> f32 word 0x3F800000; bf16 packs 0x40003F80
    const bool isbf = (((const unsigned int*)facp)[0] != 0x3F800000u);

    const int pair = blockIdx.x;             // 0..63
    const int y    = blockIdx.y;             // 0..31
    const int tid  = threadIdx.x;            // 0..255
    const int n0   = y * CHUNK + tid;

    const float MINF = (float)(40.0 / 11025.0);
    const float FSC  = (float)(3960.0 / 11025.0);

    __shared__ float sR[NF];
    __shared__ float sP[NF];                 // r^(4y), alias-masked to 0

    const float f0v = rfl(ldin(f0p, pair, isbf));
    const float sf0 = MINF + FSC * f0v;      // < 0.37
    const unsigned int Q1 = (unsigned int)((double)sf0 * 4294967296.0 + 0.5);

    if (tid < NF) {
        const float r   = ldin(resp, pair * NF + tid, isbf);
        const float fac = ldin(facp, tid, isbf);
        float P = exp2f(log2f(r) * (float)(4 * y));   // r^(4y); y==0 -> 1
        if (sf0 * fac >= 1.0f) P = 0.0f;              // aliased harmonic
        sR[tid] = r;
        sP[tid] = P;
    }
    __syncthreads();

    const float c0raw = (n0 + 0.5f) * (1.0f / 256.0f) - 0.5f;
    // frame-endpoint exponent i0c+1 is 4y (lo half, y>0) or 4y+1 (hi half / y==0)
    const bool useR1 = (tid >= 128) || (y == 0);

    float E[NF];     // per-thread env state (frame endpoint M, then env value)
    float Rg[NF];    // uniform -> SGPRs
    #pragma unroll
    for (int f4 = 0; f4 < NF; f4 += 4) {
        const float4 p4 = *(const float4*)&sP[f4];   // ds_read_b128, broadcast
        const float4 r4 = *(const float4*)&sR[f4];
        Rg[f4+0] = rfl(r4.x); Rg[f4+1] = rfl(r4.y);
        Rg[f4+2] = rfl(r4.z); Rg[f4+3] = rfl(r4.w);
        E[f4+0] = useR1 ? p4.x * Rg[f4+0] : p4.x;
        E[f4+1] = useR1 ? p4.y * Rg[f4+1] : p4.y;
        E[f4+2] = useR1 ? p4.z * Rg[f4+2] : p4.z;
        E[f4+3] = useR1 ? p4.w * Rg[f4+3] : p4.w;
    }

    const int obase = pair * NSAMP + n0;

    if (y != 0 && y != CHUNKS - 1) {
        // ---- interior: fold w0 once, then env_k = env_0 * r^k ----
        const float w0 = c0raw - floorf(c0raw);      // no clamps possible
        #pragma unroll
        for (int f = 0; f < NF; ++f) {
            const float M = E[f];
            E[f] = fmaf(w0, fmaf(M, Rg[f], -M), M);  // M + w0*(M*r - M)
        }
        #pragma unroll 1
        for (int k = 0; k < KIT; ++k) {
            const unsigned int nn = (unsigned int)(n0 + (k << 8) + 1);
            const unsigned int qn = Q1 * nn;         // phase step, u32 turns
            const unsigned int q4 = qn << 2;
            unsigned int p0 = qn, p1 = qn + qn, p2 = qn + qn + qn, p3 = q4;
            float a0 = 0.f, a1 = 0.f, a2 = 0.f, a3 = 0.f;
            #pragma unroll
            for (int f = 0; f < NF; f += 4) {
                a0 = fmaf(E[f+0], __builtin_amdgcn_sinf((float)p0 * 0x1p-32f), a0);
                a1 = fmaf(E[f+1], __builtin_amdgcn_sinf((float)p1 * 0x1p-32f), a1);
                a2 = fmaf(E[f+2], __builtin_amdgcn_sinf((float)p2 * 0x1p-32f), a2);
                a3 = fmaf(E[f+3], __builtin_amdgcn_sinf((float)p3 * 0x1p-32f), a3);
                E[f+0] *= Rg[f+0]; E[f+1] *= Rg[f+1];
                E[f+2] *= Rg[f+2]; E[f+3] *= Rg[f+3];
                p0 += q4; p1 += q4; p2 += q4; p3 += q4;
            }
            const float acc = (a0 + a1) + (a2 + a3);
            const int o = obase + (k << 8);
            if (isbf) ((__hip_bfloat16*)outp)[o] = __float2bfloat16(acc);
            else      ((float*)outp)[o] = acc;
        }
    } else {
        // ---- edge blocks (y==0 clamp-low, y==31 clamp-high): general interp ----
        const float c0 = fminf(fmaxf(c0raw, 0.0f), 127.0f);
        const float w0 = c0 - floorf(c0);
        const float c1 = c0raw + 1.0f;
        const float w1 = c1 - floorf(c1);
        const bool clampLow = (y == 0) && (c0raw < 0.0f);
        #pragma unroll 1
        for (int k = 0; k < KIT; ++k) {
            const unsigned int nn = (unsigned int)(n0 + (k << 8) + 1);
            const unsigned int qn = Q1 * nn;
            const unsigned int q4 = qn << 2;
            unsigned int p[4] = { qn, qn + qn, qn + qn + qn, q4 };
            const float wk = (k == 0)
                ? w0 : ((c0raw + (float)k > 127.0f) ? 0.0f : w1);
            const bool adv = !((k == 0) && clampLow); // clamped lanes hold frame 0
            float a[4] = { 0.f, 0.f, 0.f, 0.f };
            #pragma unroll
            for (int f = 0; f < NF; ++f) {
                const int j = f & 3;
                const float M   = E[f];
                const float An  = M * Rg[f];
                const float env = fmaf(wk, An - M, M);
                a[j] = fmaf(env, __builtin_amdgcn_sinf((float)p[j] * 0x1p-32f), a[j]);
                E[f] = adv ? An : M;
                p[j] += q4;
            }
            const float acc = (a[0] + a[1]) + (a[2] + a[3]);
            const int o = obase + (k << 8);
            if (isbf) ((__hip_bfloat16*)outp)[o] = __float2bfloat16(acc);
            else      ((float*)outp)[o] = acc;
        }
    }
}

extern "C" void kernel_launch(void* const* d_in, const int* in_sizes, int n_in,
                              void* d_out, int out_size, void* d_ws, size_t ws_size,
                              hipStream_t stream) {
    (void)in_sizes; (void)n_in; (void)out_size; (void)d_ws; (void)ws_size;
    dim3 grid(NPAIR, CHUNKS);   // 64 x 32 = 2048 blocks, 8192 waves
    dim3 block(256);
    reson_kernel<<<grid, block, 0, stream>>>(d_in[0], d_in[1], d_in[2], d_out);
}

// Round 5
// 74.530 us; speedup vs baseline: 1.2140x; 1.2140x over previous
//
#include <hip/hip_runtime.h>
#include <hip/hip_bf16.h>

// Resonance synth: out(b,e,n) = sum_f env_f(n) * sin(2*pi*freq_f*(n+1))
//   freq_f = (MIN + SCALE*f0_be)*(f+1), aliased (>=1.0) harmonics contribute 0
//   env_f(n) = linear frame->sample interp of res^(t+1), 256 samples/frame.
//
// Round 5 (discriminator):
//  - __launch_bounds__(256,4): 128-VGPR cap vs ~60 demand -> zero spill risk
//    (R2's FETCH_SIZE=108MB showed spills can silently eat 20+ us here)
//  - grid 64x16 = 1024 blocks = exactly 4 blocks/CU, tail-free; KIT=8
//    amortizes the prologue transcendentals
//  - u32 fixed-point phase add-chains (no per-f mul), env *=R recurrence,
//    R[] in SGPRs via readfirstlane, 4 independent accumulators

#define NSAMP 32768
#define NFRM  128
#define NF    32
#define NPAIR 64
#define CHUNKS 16
#define CHUNK (NSAMP / CHUNKS)   // 2048 samples per block
#define KIT   (CHUNK / 256)      // 8 samples per thread, 8 frames per block

__device__ __forceinline__ float ldin(const void* p, int i, bool isbf) {
    if (isbf) {
        unsigned int w = ((unsigned int)((const unsigned short*)p)[i]) << 16;
        float f; __builtin_memcpy(&f, &w, 4); return f;
    }
    return ((const float*)p)[i];
}

// force a block-uniform float into an SGPR
__device__ __forceinline__ float rfl(float x) {
    int i; __builtin_memcpy(&i, &x, 4);
    i = __builtin_amdgcn_readfirstlane(i);
    float f; __builtin_memcpy(&f, &i, 4); return f;
}

extern "C" __global__ __launch_bounds__(256, 4)
void reson_kernel(const void* __restrict__ f0p,
                  const void* __restrict__ resp,
                  const void* __restrict__ facp,
                  void* __restrict__ outp)
{
    // dtype sniff: factors[0]==1.0f -> f32 word 0x3F800000; bf16 packs 0x40003F80
    const bool isbf = (((const unsigned int*)facp)[0] != 0x3F800000u);

    const int pair = blockIdx.x;             // 0..63
    const int y    = blockIdx.y;             // 0..15
    const int tid  = threadIdx.x;            // 0..255
    const int n0   = y * CHUNK + tid;

    const float MINF = (float)(40.0 / 11025.0);
    const float FSC  = (float)(3960.0 / 11025.0);

    __shared__ float sR[NF];
    __shared__ float sP[NF];                 // r^(8y), alias-masked to 0

    const float f0v = rfl(ldin(f0p, pair, isbf));
    const float sf0 = MINF + FSC * f0v;      // < 0.37
    const unsigned int Q1 = (unsigned int)((double)sf0 * 4294967296.0 + 0.5);

    if (tid < NF) {
        const float r   = ldin(resp, pair * NF + tid, isbf);
        const float fac = ldin(facp, tid, isbf);
        float P = exp2f(log2f(r) * (float)(8 * y));   // r^(8y); y==0 -> 1
        if (sf0 * fac >= 1.0f) P = 0.0f;              // aliased harmonic
        sR[tid] = r;
        sP[tid] = P;
    }
    __syncthreads();

    const float c0raw = (n0 + 0.5f) * (1.0f / 256.0f) - 0.5f;
    // frame-endpoint exponent i0c+1 is 8y (lo half, y>0) or 8y+1 (hi half / y==0)
    const bool useR1 = (tid >= 128) || (y == 0);

    float E[NF];     // per-thread env state
    float Rg[NF];    // block-uniform -> SGPRs
    #pragma unroll
    for (int f4 = 0; f4 < NF; f4 += 4) {
        const float4 p4 = *(const float4*)&sP[f4];   // ds_read_b128, broadcast
        const float4 r4 = *(const float4*)&sR[f4];
        Rg[f4+0] = rfl(r4.x); Rg[f4+1] = rfl(r4.y);
        Rg[f4+2] = rfl(r4.z); Rg[f4+3] = rfl(r4.w);
        E[f4+0] = useR1 ? p4.x * Rg[f4+0] : p4.x;
        E[f4+1] = useR1 ? p4.y * Rg[f4+1] : p4.y;
        E[f4+2] = useR1 ? p4.z * Rg[f4+2] : p4.z;
        E[f4+3] = useR1 ? p4.w * Rg[f4+3] : p4.w;
    }

    const int obase = pair * NSAMP + n0;

    if (y != 0 && y != CHUNKS - 1) {
        // ---- interior: fold w0 once, then env_k = env_0 * r^k ----
        const float w0 = c0raw - floorf(c0raw);      // no clamps possible
        #pragma unroll
        for (int f = 0; f < NF; ++f) {
            const float M = E[f];
            E[f] = fmaf(w0, fmaf(M, Rg[f], -M), M);  // M + w0*(M*r - M)
        }
        #pragma unroll 1
        for (int k = 0; k < KIT; ++k) {
            const unsigned int nn = (unsigned int)(n0 + (k << 8) + 1);
            const unsigned int qn = Q1 * nn;         // phase step, u32 turns
            const unsigned int q4 = qn << 2;
            unsigned int p0 = qn, p1 = qn + qn, p2 = qn + qn + qn, p3 = q4;
            float a0 = 0.f, a1 = 0.f, a2 = 0.f, a3 = 0.f;
            #pragma unroll
            for (int f = 0; f < NF; f += 4) {
                a0 = fmaf(E[f+0], __builtin_amdgcn_sinf((float)p0 * 0x1p-32f), a0);
                a1 = fmaf(E[f+1], __builtin_amdgcn_sinf((float)p1 * 0x1p-32f), a1);
                a2 = fmaf(E[f+2], __builtin_amdgcn_sinf((float)p2 * 0x1p-32f), a2);
                a3 = fmaf(E[f+3], __builtin_amdgcn_sinf((float)p3 * 0x1p-32f), a3);
                E[f+0] *= Rg[f+0]; E[f+1] *= Rg[f+1];
                E[f+2] *= Rg[f+2]; E[f+3] *= Rg[f+3];
                p0 += q4; p1 += q4; p2 += q4; p3 += q4;
            }
            const float acc = (a0 + a1) + (a2 + a3);
            const int o = obase + (k << 8);
            if (isbf) ((__hip_bfloat16*)outp)[o] = __float2bfloat16(acc);
            else      ((float*)outp)[o] = acc;
        }
    } else {
        // ---- edge blocks (y==0 clamp-low, y==15 clamp-high): general interp ----
        const float c0 = fminf(fmaxf(c0raw, 0.0f), 127.0f);
        const float w0 = c0 - floorf(c0);
        const float c1 = c0raw + 1.0f;
        const float w1 = c1 - floorf(c1);
        const bool clampLow = (y == 0) && (c0raw < 0.0f);
        #pragma unroll 1
        for (int k = 0; k < KIT; ++k) {
            const unsigned int nn = (unsigned int)(n0 + (k << 8) + 1);
            const unsigned int qn = Q1 * nn;
            const unsigned int q4 = qn << 2;
            unsigned int p[4] = { qn, qn + qn, qn + qn + qn, q4 };
            const float wk = (k == 0)
                ? w0 : ((c0raw + (float)k > 127.0f) ? 0.0f : w1);
            const bool adv = !((k == 0) && clampLow); // clamped lanes hold frame 0
            float a[4] = { 0.f, 0.f, 0.f, 0.f };
            #pragma unroll
            for (int f = 0; f < NF; ++f) {
                const int j = f & 3;
                const float M   = E[f];
                const float An  = M * Rg[f];
                const float env = fmaf(wk, An - M, M);
                a[j] = fmaf(env, __builtin_amdgcn_sinf((float)p[j] * 0x1p-32f), a[j]);
                E[f] = adv ? An : M;
                p[j] += q4;
            }
            const float acc = (a[0] + a[1]) + (a[2] + a[3]);
            const int o = obase + (k << 8);
            if (isbf) ((__hip_bfloat16*)outp)[o] = __float2bfloat16(acc);
            else      ((float*)outp)[o] = acc;
        }
    }
}

extern "C" void kernel_launch(void* const* d_in, const int* in_sizes, int n_in,
                              void* d_out, int out_size, void* d_ws, size_t ws_size,
                              hipStream_t stream) {
    (void)in_sizes; (void)n_in; (void)out_size; (void)d_ws; (void)ws_size;
    dim3 grid(NPAIR, CHUNKS);   // 64 x 16 = 1024 blocks = 4 blocks/CU, tail-free
    dim3 block(256);
    reson_kernel<<<grid, block, 0, stream>>>(d_in[0], d_in[1], d_in[2], d_out);
}

// Round 6
// 66.221 us; speedup vs baseline: 1.3663x; 1.1255x over previous
//
#include <hip/hip_runtime.h>
#include <hip/hip_bf16.h>

// Resonance synth: out(b,e,n) = sum_f env_f(n) * sin(2*pi*freq_f*(n+1))
//   freq_f = (MIN + SCALE*f0_be)*(f+1), aliased (>=1.0) harmonics contribute 0
//   env_f(n) = linear frame->sample interp of res^(t+1), 256 samples/frame.
//
// Round 6: Chebyshev harmonic recurrence.
//   All 32 harmonics share base angle theta = 2*pi*frac(sf0*nn) (u32 phase).
//   sin(f*theta) via s_{f+1} = 2cos(theta)*s_f - s_{f-1}: ONE sin + ONE cos
//   per sample instead of 32 sins. Recurrence is a rotation (unit-circle
//   eigenvalues) -> rounding error ~1e-4 max, far below bf16 quantum.
//   Env: E[f] *= R[f] per k-step (interior), R in SGPRs. ~50 VGPR state.

#define NSAMP 32768
#define NFRM  128
#define NF    32
#define NPAIR 64
#define CHUNKS 16
#define CHUNK (NSAMP / CHUNKS)   // 2048 samples per block
#define KIT   (CHUNK / 256)      // 8 samples per thread, 8 frames per block

__device__ __forceinline__ float ldin(const void* p, int i, bool isbf) {
    if (isbf) {
        unsigned int w = ((unsigned int)((const unsigned short*)p)[i]) << 16;
        float f; __builtin_memcpy(&f, &w, 4); return f;
    }
    return ((const float*)p)[i];
}

// force a block-uniform float into an SGPR
__device__ __forceinline__ float rfl(float x) {
    int i; __builtin_memcpy(&i, &x, 4);
    i = __builtin_amdgcn_readfirstlane(i);
    float f; __builtin_memcpy(&f, &i, 4); return f;
}

extern "C" __global__ __launch_bounds__(256, 4)
void reson_kernel(const void* __restrict__ f0p,
                  const void* __restrict__ resp,
                  const void* __restrict__ facp,
                  void* __restrict__ outp)
{
    // dtype sniff: factors[0]==1.0f -> f32 word 0x3F800000; bf16 packs 0x40003F80
    const bool isbf = (((const unsigned int*)facp)[0] != 0x3F800000u);

    const int pair = blockIdx.x;             // 0..63
    const int y    = blockIdx.y;             // 0..15
    const int tid  = threadIdx.x;            // 0..255
    const int n0   = y * CHUNK + tid;

    const float MINF = (float)(40.0 / 11025.0);
    const float FSC  = (float)(3960.0 / 11025.0);

    __shared__ float sR[NF];
    __shared__ float sP[NF];                 // r^(8y), alias-masked to 0

    const float f0v = rfl(ldin(f0p, pair, isbf));
    const float sf0 = MINF + FSC * f0v;      // < 0.37
    const unsigned int Q1 = (unsigned int)((double)sf0 * 4294967296.0 + 0.5);

    if (tid < NF) {
        const float r   = ldin(resp, pair * NF + tid, isbf);
        const float fac = ldin(facp, tid, isbf);
        float P = exp2f(log2f(r) * (float)(8 * y));   // r^(8y); y==0 -> 1
        if (sf0 * fac >= 1.0f) P = 0.0f;              // aliased harmonic
        sR[tid] = r;
        sP[tid] = P;
    }
    __syncthreads();

    const float c0raw = (n0 + 0.5f) * (1.0f / 256.0f) - 0.5f;
    // frame-endpoint exponent i0c+1 is 8y (lo half, y>0) or 8y+1 (hi half / y==0)
    const bool useR1 = (tid >= 128) || (y == 0);

    float E[NF];     // per-thread env state
    float Rg[NF];    // block-uniform -> SGPRs
    #pragma unroll
    for (int f4 = 0; f4 < NF; f4 += 4) {
        const float4 p4 = *(const float4*)&sP[f4];   // ds_read_b128, broadcast
        const float4 r4 = *(const float4*)&sR[f4];
        Rg[f4+0] = rfl(r4.x); Rg[f4+1] = rfl(r4.y);
        Rg[f4+2] = rfl(r4.z); Rg[f4+3] = rfl(r4.w);
        E[f4+0] = useR1 ? p4.x * Rg[f4+0] : p4.x;
        E[f4+1] = useR1 ? p4.y * Rg[f4+1] : p4.y;
        E[f4+2] = useR1 ? p4.z * Rg[f4+2] : p4.z;
        E[f4+3] = useR1 ? p4.w * Rg[f4+3] : p4.w;
    }

    const int obase = pair * NSAMP + n0;

    if (y != 0 && y != CHUNKS - 1) {
        // ---- interior: fold w0 once, then env_k = env_0 * r^k ----
        const float w0 = c0raw - floorf(c0raw);      // no clamps possible
        #pragma unroll
        for (int f = 0; f < NF; ++f) {
            const float M = E[f];
            E[f] = fmaf(w0, fmaf(M, Rg[f], -M), M);  // M + w0*(M*r - M)
        }
        #pragma unroll 1
        for (int k = 0; k < KIT; ++k) {
            const unsigned int nn = (unsigned int)(n0 + (k << 8) + 1);
            const unsigned int qn = Q1 * nn;          // base phase, u32 turns
            const float t  = (float)qn * 0x1p-32f;    // [0,1) revolutions
            const float s1 = __builtin_amdgcn_sinf(t);
            const float c1 = __builtin_amdgcn_cosf(t);
            const float k2 = c1 + c1;                 // 2*cos(theta)
            float sp = 0.0f, sc = s1;                 // sin(0), sin(theta)
            float a0 = 0.0f, a1 = 0.0f;
            #pragma unroll
            for (int f = 0; f < NF; ++f) {
                if (f & 1) a1 = fmaf(E[f], sc, a1);
                else       a0 = fmaf(E[f], sc, a0);
                E[f] *= Rg[f];
                const float sn = fmaf(k2, sc, -sp);   // sin((f+2)*theta)
                sp = sc; sc = sn;
            }
            const float acc = a0 + a1;
            const int o = obase + (k << 8);
            if (isbf) ((__hip_bfloat16*)outp)[o] = __float2bfloat16(acc);
            else      ((float*)outp)[o] = acc;
        }
    } else {
        // ---- edge blocks (y==0 clamp-low, y==15 clamp-high): general interp ----
        const float c0 = fminf(fmaxf(c0raw, 0.0f), 127.0f);
        const float w0 = c0 - floorf(c0);
        const float c1e = c0raw + 1.0f;
        const float w1 = c1e - floorf(c1e);
        const bool clampLow = (y == 0) && (c0raw < 0.0f);
        #pragma unroll 1
        for (int k = 0; k < KIT; ++k) {
            const unsigned int nn = (unsigned int)(n0 + (k << 8) + 1);
            const unsigned int qn = Q1 * nn;
            const float t  = (float)qn * 0x1p-32f;
            const float s1 = __builtin_amdgcn_sinf(t);
            const float cc = __builtin_amdgcn_cosf(t);
            const float k2 = cc + cc;
            float sp = 0.0f, sc = s1;
            const float wk = (k == 0)
                ? w0 : ((c0raw + (float)k > 127.0f) ? 0.0f : w1);
            const bool adv = !((k == 0) && clampLow); // clamped lanes hold frame 0
            float a0 = 0.0f, a1 = 0.0f;
            #pragma unroll
            for (int f = 0; f < NF; ++f) {
                const float M   = E[f];
                const float An  = M * Rg[f];
                const float env = fmaf(wk, An - M, M);
                if (f & 1) a1 = fmaf(env, sc, a1);
                else       a0 = fmaf(env, sc, a0);
                E[f] = adv ? An : M;
                const float sn = fmaf(k2, sc, -sp);
                sp = sc; sc = sn;
            }
            const float acc = a0 + a1;
            const int o = obase + (k << 8);
            if (isbf) ((__hip_bfloat16*)outp)[o] = __float2bfloat16(acc);
            else      ((float*)outp)[o] = acc;
        }
    }
}

extern "C" void kernel_launch(void* const* d_in, const int* in_sizes, int n_in,
                              void* d_out, int out_size, void* d_ws, size_t ws_size,
                              hipStream_t stream) {
    (void)in_sizes; (void)n_in; (void)out_size; (void)d_ws; (void)ws_size;
    dim3 grid(NPAIR, CHUNKS);   // 64 x 16 = 1024 blocks = 4 blocks/CU, tail-free
    dim3 block(256);
    reson_kernel<<<grid, block, 0, stream>>>(d_in[0], d_in[1], d_in[2], d_out);
}